// Round 14
// baseline (12607.870 us; speedup 1.0000x reference)
//
#include <hip/hip_runtime.h>
#include <hip/hip_fp16.h>

// Problem constants
#define TT 2048
#define II 1739
#define IIP 1760              // II zero-padded to a multiple of 32 (f16 GEMM K)
#define HN 256
#define H3 768
#define L2E 1.44269504088896f
#define NCAND 24              // scan-pair election candidates (>8 -> pigeonhole)

typedef _Float16 h2 __attribute__((ext_vector_type(2)));
typedef _Float16 h8 __attribute__((ext_vector_type(8)));
typedef float f4 __attribute__((ext_vector_type(4)));

__device__ __forceinline__ float fdot2(h2 a, h2 b, float c) {
#if defined(__has_builtin)
#if __has_builtin(__builtin_amdgcn_fdot2)
  return __builtin_amdgcn_fdot2(a, b, c, false);
#else
  return fmaf((float)a[0], (float)b[0], fmaf((float)a[1], (float)b[1], c));
#endif
#else
  return fmaf((float)a[0], (float)b[0], fmaf((float)a[1], (float)b[1], c));
#endif
}

__device__ __forceinline__ float fast_exp2(float x) {
#if defined(__has_builtin)
#if __has_builtin(__builtin_amdgcn_exp2f)
  return __builtin_amdgcn_exp2f(x);
#else
  return exp2f(x);
#endif
#else
  return exp2f(x);
#endif
}

__device__ __forceinline__ float fast_rcp(float x) {
#if defined(__has_builtin)
#if __has_builtin(__builtin_amdgcn_rcpf)
  return __builtin_amdgcn_rcpf(x);
#else
  return 1.f / x;
#endif
#else
  return 1.f / x;
#endif
}

template <int CTRL>
__device__ __forceinline__ float dpp_qperm(float v) {
  int r = __builtin_amdgcn_update_dpp(0, __builtin_bit_cast(int, v), CTRL, 0xF, 0xF, true);
  return __builtin_bit_cast(float, r);
}

__device__ __forceinline__ h8 h8zero() {
  h8 v;
#pragma unroll
  for (int j = 0; j < 8; ++j) v[j] = (_Float16)0.f;
  return v;
}

// ---------------------------------------------------------------------------
// One-time f32 -> f16 weight conversion (zero-padded K for the W_ih's).
// ---------------------------------------------------------------------------
#define WSEG (768 * IIP)
#define OSEG (II * HN)
__global__ __launch_bounds__(256) void prep_f16(
    const float* __restrict__ We, const float* __restrict__ Wd,
    const float* __restrict__ Wo,
    _Float16* __restrict__ weh, _Float16* __restrict__ wdh,
    _Float16* __restrict__ woh) {
  const int total = 2 * WSEG + OSEG;
  for (int i = blockIdx.x * 256 + threadIdx.x; i < total; i += gridDim.x * 256) {
    if (i < WSEG) {
      int r = i / IIP, k = i - r * IIP;
      weh[i] = (k < II) ? (_Float16)We[(size_t)r * II + k] : (_Float16)0.f;
    } else if (i < 2 * WSEG) {
      int j = i - WSEG;
      int r = j / IIP, k = j - r * IIP;
      wdh[j] = (k < II) ? (_Float16)Wd[(size_t)r * II + k] : (_Float16)0.f;
    } else {
      int j = i - 2 * WSEG;
      woh[j] = (_Float16)Wo[j];
    }
  }
}

// ---------------------------------------------------------------------------
// MFMA f16 GEMM tile body (r11, verified): C = ((A_f32 @ B16^T)+bias)*scale.
// 256 logical threads (512-thread callers pass tid&255: duplicate lanes redo
// identical work -- benign WAW, proven r10/r13).
// ---------------------------------------------------------------------------
__device__ __forceinline__ void gemm16_tile(
    int tid, int bx, int by,
    const float* __restrict__ A, int K,
    const _Float16* __restrict__ B16, int N, int Kp,
    const float* __restrict__ bias1, const float* __restrict__ bias2, int b2lim,
    float s_lo, float s_hi, int slim,
    float* __restrict__ C,
    _Float16 (*As)[40], _Float16 (*Bs)[40]) {
  const int w = tid >> 6, lane = tid & 63;
  const int col = lane & 15, kg = lane >> 4;
  const int m0 = by * 64, n0 = bx * 64;
  const int srow = tid >> 2, skq = tid & 3;
  f4 acc[4];
#pragma unroll
  for (int m = 0; m < 4; ++m) acc[m] = f4{0.f, 0.f, 0.f, 0.f};

  for (int k0 = 0; k0 < Kp; k0 += 32) {
    const int kk = k0 + skq * 8;
    h8 av = h8zero(), bv = h8zero();
    {
      const float* ap = A + (size_t)(m0 + srow) * K + kk;
      if (kk + 8 <= K) {
        float4 f0, f1;
        __builtin_memcpy(&f0, ap, 16);
        __builtin_memcpy(&f1, ap + 4, 16);
        av[0] = (_Float16)f0.x; av[1] = (_Float16)f0.y;
        av[2] = (_Float16)f0.z; av[3] = (_Float16)f0.w;
        av[4] = (_Float16)f1.x; av[5] = (_Float16)f1.y;
        av[6] = (_Float16)f1.z; av[7] = (_Float16)f1.w;
      } else if (kk < K) {
#pragma unroll
        for (int j = 0; j < 8; ++j)
          if (kk + j < K) av[j] = (_Float16)ap[j];
      }
    }
    {
      const int bn = n0 + srow;
      if (bn < N) bv = *(const h8*)(B16 + (size_t)bn * Kp + kk);
    }
    __syncthreads();
    *(h8*)&As[srow][skq * 8] = av;
    *(h8*)&Bs[srow][skq * 8] = bv;
    __syncthreads();
    h8 b = *(const h8*)&Bs[w * 16 + col][kg * 8];
#pragma unroll
    for (int m = 0; m < 4; ++m) {
      h8 a = *(const h8*)&As[m * 16 + col][kg * 8];
      acc[m] = __builtin_amdgcn_mfma_f32_16x16x32_f16(a, b, acc[m], 0, 0, 0);
    }
  }

  const int n = n0 + w * 16 + col;
  if (n < N) {
    float bb = bias1[n];
    if (bias2 && n < b2lim) bb += bias2[n];
    const float s = (n < slim) ? s_lo : s_hi;
#pragma unroll
    for (int m = 0; m < 4; ++m) {
      const int mr = m0 + m * 16 + kg * 4;
#pragma unroll
      for (int r = 0; r < 4; ++r)
        C[(size_t)(mr + r) * N + n] = (acc[m][r] + bb) * s;
    }
  }
}

__global__ __launch_bounds__(256) void gemm16(
    const float* __restrict__ A, int K,
    const _Float16* __restrict__ B16, int N, int Kp,
    const float* __restrict__ bias1, const float* __restrict__ bias2, int b2lim,
    float s_lo, float s_hi, int slim,
    float* __restrict__ C) {
  __shared__ _Float16 As[64][40];
  __shared__ _Float16 Bs[64][40];
  gemm16_tile(threadIdx.x, blockIdx.x, blockIdx.y, A, K, B16, N, Kp,
              bias1, bias2, b2lim, s_lo, s_hi, slim, C, As, Bs);
}

// ---------------------------------------------------------------------------
// Same-XCD pair election. Each candidate block's tid0 reads its physical XCD
// (s_getreg HW_REG_XCC_ID, HW-verified on gfx950), counts into el[xcd]; the
// first XCD to collect 2 blocks claims the scan via CAS on el[8] (0 = unset,
// xcd+1 = chosen). Winners return role 0/1; everyone else returns -1.
// Deadlock-free: with NCAND=24 > 8 XCDs, some counter reaches 2 (pigeonhole),
// so el[8] is always set; losers then exit. A misread XCC_ID only degrades
// placement (cross-XCD pair = r13 speed), never correctness.
// ---------------------------------------------------------------------------
__device__ int elect_role(uint* __restrict__ el) {
  __shared__ int s_role;
  if (threadIdx.x == 0) {
    uint xcc = 0;
    asm volatile("s_getreg_b32 %0, hwreg(HW_REG_XCC_ID)" : "=s"(xcc));
    xcc &= 7u;
    uint my = atomicAdd(&el[xcc], 1u);
    int role = -1;
    if (my == 1u) atomicCAS(&el[8], 0u, xcc + 1u);
    if (my < 2u) {
      uint c;
      while ((c = __hip_atomic_load(&el[8], __ATOMIC_ACQUIRE,
                                    __HIP_MEMORY_SCOPE_AGENT)) == 0u)
        __builtin_amdgcn_s_sleep(2);
      if (c == xcc + 1u) role = (int)my;
    }
    s_role = role;
  }
  __syncthreads();
  return s_role;
}

// ---------------------------------------------------------------------------
// TWO-CU GRU scan, same-XCD pair, overlapped exchange. Role b owns hidden
// units [128b, 128b+128). Quad q owns unit u = 128b+q; lane kc covers
// 64 k-values split 32 LOCAL + 32 REMOTE:
//   local  h-dwords [64b   +16kc, +16)  (own half -> LDS, no peer dep)
//   remote h-dwords [64peer+16kc, +16)  (peer half -> global slots)
// Step: spin peer flag (lane0/wave) -> issue 16 atomic slot loads ->
// local 48 fdot2 from LDS (hides the load latency) -> remote 48 fdot2 ->
// butterfly -> gates -> publish (LDS nxt + slots + hs) -> barrier -> flag.
// Slot/flag primitives are byte-identical to r13 (correctness proven there,
// absmax exactly 0.0078125); only placement and overlap changed.
// ---------------------------------------------------------------------------
__device__ void gru_scan2(
    int b,
    const float* __restrict__ xp, const float* __restrict__ Whh,
    const float* __restrict__ bhh, const float* __restrict__ h0,
    float* __restrict__ hs_out, float* __restrict__ hT_out,
    uint* __restrict__ slots, uint* __restrict__ flags,
    uint* hbufd /* LDS, 2x160 dwords: dbuf, 4 chunks @ stride 40 */) {
  const int tid = threadIdx.x;
  const int lane = tid & 63;
  const int wv = tid >> 6;              // 0..7
  const int kc = lane & 3;
  const int q = wv * 16 + (lane >> 2);  // 0..127 local unit index
  const int u = 128 * b + q;
  const int peer = 1 - b;
  uint* myflag = flags + b * 64;
  uint* pflag = flags + peer * 64;

  // Weights: per row, 16 local-dword pairs then 16 remote-dword pairs.
  h2 wreg[3][32];
#pragma unroll
  for (int gg = 0; gg < 3; ++gg) {
    const float sc = (gg == 2) ? (2.f * L2E) : L2E;
    const float* wr = Whh + (size_t)(gg * HN + u) * HN;
    const int dl0 = 64 * b + 16 * kc, dr0 = 64 * peer + 16 * kc;
#pragma unroll
    for (int i = 0; i < 16; ++i) {
      float2 f = *(const float2*)(wr + 2 * (dl0 + i));
      wreg[gg][i] = h2{(_Float16)(f.x * sc), (_Float16)(f.y * sc)};
    }
#pragma unroll
    for (int i = 0; i < 16; ++i) {
      float2 f = *(const float2*)(wr + 2 * (dr0 + i));
      wreg[gg][16 + i] = h2{(_Float16)(f.x * sc), (_Float16)(f.y * sc)};
    }
  }

  float hj = h0 ? h0[u] : 0.f;
  const float bhn = bhh[2 * HN + u] * (2.f * L2E);

  // Prologue: local half of h_0 -> LDS buf0 + slot parity 0; flag = 1.
  if (tid < 64) {
    const int d = 64 * b + tid;
    float a = h0 ? h0[2 * d] : 0.f;
    float c = h0 ? h0[2 * d + 1] : 0.f;
    h2 pv = h2{(_Float16)a, (_Float16)c};
    uint pw = __builtin_bit_cast(uint, pv);
    hbufd[(d >> 5) * 40 + (d & 31)] = pw;
    __hip_atomic_store(&slots[b * 64 + tid], pw, __ATOMIC_RELAXED,
                       __HIP_MEMORY_SCOPE_AGENT);
  }
  __syncthreads();
  if (tid == 0)
    __hip_atomic_store(myflag, 1u, __ATOMIC_RELEASE, __HIP_MEMORY_SCOPE_AGENT);

  // LDS dword offset of this lane's local 16-dword window (within a buffer).
  const int lc = (2 * b + (kc >> 1)) * 40 + (kc & 1) * 16;

  for (int t = 0; t < TT; ++t) {
    const int cur = (t & 1) * 160, nxt = ((t + 1) & 1) * 160;

    // x-projection for unit u (redundant across the quad's 4 lanes).
    const float* xpt = xp + (size_t)t * H3 + u;
    float xr = xpt[0], xz = xpt[HN], xn = xpt[2 * HN];

    // Wait for peer's h_t (lane0 per wave; wave lockstep gates the rest).
    if (lane == 0) {
      while (__hip_atomic_load(pflag, __ATOMIC_ACQUIRE,
                               __HIP_MEMORY_SCOPE_AGENT) < (uint)(t + 1))
        __builtin_amdgcn_s_sleep(1);
    }
    // Issue the 16 remote h loads (atomic relaxed AGENT = r13-proven path).
    uint* rs = slots + (t & 1) * 128 + peer * 64 + 16 * kc;
    uint rr[16];
#pragma unroll
    for (int i = 0; i < 16; ++i)
      rr[i] = __hip_atomic_load(rs + i, __ATOMIC_RELAXED,
                                __HIP_MEMORY_SCOPE_AGENT);

    // Local half matvec (LDS; runs while the remote loads are in flight).
    const uint* lb = hbufd + cur + lc;
    float a0 = 0.f, a1 = 0.f, a2 = 0.f;
#pragma unroll
    for (int j = 0; j < 4; ++j) {
      uint4 v = *(const uint4*)(lb + 4 * j);
      uint hv[4] = {v.x, v.y, v.z, v.w};
#pragma unroll
      for (int p = 0; p < 4; ++p) {
        h2 hp = __builtin_bit_cast(h2, hv[p]);
        a0 = fdot2(wreg[0][4 * j + p], hp, a0);
        a1 = fdot2(wreg[1][4 * j + p], hp, a1);
        a2 = fdot2(wreg[2][4 * j + p], hp, a2);
      }
    }
    // Remote half matvec (registers; compiler inserts the vmcnt waits).
#pragma unroll
    for (int i = 0; i < 16; ++i) {
      h2 hp = __builtin_bit_cast(h2, rr[i]);
      a0 = fdot2(wreg[0][16 + i], hp, a0);
      a1 = fdot2(wreg[1][16 + i], hp, a1);
      a2 = fdot2(wreg[2][16 + i], hp, a2);
    }

    // Quad butterfly: all 4 lanes end with the full k-sum.
    a0 += dpp_qperm<0xB1>(a0); a0 += dpp_qperm<0x4E>(a0);
    a1 += dpp_qperm<0xB1>(a1); a1 += dpp_qperm<0x4E>(a1);
    a2 += dpp_qperm<0xB1>(a2); a2 += dpp_qperm<0x4E>(a2);

    // Gates (args pre-scaled by log2e / 2log2e).
    float r = fast_rcp(1.f + fast_exp2(-(xr + a0)));
    float z = fast_rcp(1.f + fast_exp2(-(xz + a1)));
    float nv = fmaf(2.f, fast_rcp(1.f + fast_exp2(-fmaf(r, a2 + bhn, xn))), -1.f);
    hj = fmaf(z, hj - nv, nv);

    // Publish h_{t+1}: lanes L, L+4 ((lane&7)==0) pair adjacent quads.
    float hj4 = __shfl(hj, lane + 4);  // uniform path
    if ((lane & 7) == 0) {
      h2 pv = h2{(_Float16)hj, (_Float16)hj4};
      uint pw = __builtin_bit_cast(uint, pv);
      const int ld = wv * 8 + (lane >> 3);
      const int dg = 64 * b + ld;
      hbufd[nxt + (dg >> 5) * 40 + (dg & 31)] = pw;
      __hip_atomic_store(&slots[((t + 1) & 1) * 128 + b * 64 + ld], pw,
                         __ATOMIC_RELAXED, __HIP_MEMORY_SCOPE_AGENT);
      if (hs_out) *(float2*)&hs_out[(size_t)t * HN + u] = make_float2(hj, hj4);
    }
    __syncthreads();  // drains vmcnt (slot stores done) + orders LDS h
    if (tid == 0)
      __hip_atomic_store(myflag, (uint)(t + 2), __ATOMIC_RELEASE,
                         __HIP_MEMORY_SCOPE_AGENT);
  }
  float hj4t = __shfl(hj, lane + 4);  // hoisted out of divergent branch
  if (hT_out && (lane & 7) == 0)
    *(float2*)&hT_out[u] = make_float2(hj, hj4t);
}

// Decoder scan: 24 candidate blocks, elected pair runs; losers exit.
__global__ __launch_bounds__(512) void gru_pair(
    const float* __restrict__ xp, const float* __restrict__ Whh,
    const float* __restrict__ bhh, const float* __restrict__ h0,
    float* __restrict__ hs_out, float* __restrict__ hT_out,
    uint* __restrict__ slots, uint* __restrict__ flags,
    uint* __restrict__ el) {
  __shared__ __align__(16) uint hbufd[2 * 160];
  int role = elect_role(el);
  if (role < 0) return;
  gru_scan2(role, xp, Whh, bhh, h0, hs_out, hT_out, slots, flags, hbufd);
}

// Encoder: candidates [0,NCAND) elect the scan pair; blocks [NCAND, +384)
// run the xpd projection (free-running, no communication -> safe).
__global__ __launch_bounds__(512) void fused_enc(
    const float* __restrict__ xpe, const float* __restrict__ Whh_e,
    const float* __restrict__ bhh_e, float* __restrict__ henc,
    uint* __restrict__ slots, uint* __restrict__ flags,
    uint* __restrict__ el,
    const float* __restrict__ x, const _Float16* __restrict__ wdh,
    const float* __restrict__ bih_d, const float* __restrict__ bhh_d,
    float* __restrict__ xpd) {
  __shared__ __align__(16) uint hbufd[2 * 160];
  __shared__ _Float16 As[64][40];
  __shared__ _Float16 Bs[64][40];
  if (blockIdx.x < NCAND) {
    int role = elect_role(el);
    if (role < 0) return;
    gru_scan2(role, xpe, Whh_e, bhh_e, nullptr, nullptr, henc,
              slots, flags, hbufd);
  } else {
    const int bb = blockIdx.x - NCAND;  // 0..383
    gemm16_tile(threadIdx.x & 255, bb % 12, bb / 12, x, II, wdh, H3, IIP,
                bih_d, bhh_d, 2 * HN, L2E, 2.f * L2E, 2 * HN, xpd, As, Bs);
  }
}

extern "C" void kernel_launch(void* const* d_in, const int* in_sizes, int n_in,
                              void* d_out, int out_size, void* d_ws, size_t ws_size,
                              hipStream_t stream) {
  const float* x     = (const float*)d_in[0];   // [1, 2048, 1739]
  const float* Wih_e = (const float*)d_in[2];   // [768, 1739]
  const float* Whh_e = (const float*)d_in[3];   // [768, 256]
  const float* bih_e = (const float*)d_in[4];   // [768]
  const float* bhh_e = (const float*)d_in[5];   // [768]
  const float* Wih_d = (const float*)d_in[6];
  const float* Whh_d = (const float*)d_in[7];
  const float* bih_d = (const float*)d_in[8];
  const float* bhh_d = (const float*)d_in[9];
  const float* Wout  = (const float*)d_in[10];  // [1739, 256]
  const float* bout  = (const float*)d_in[11];  // [1739]
  float* out = (float*)d_out;                   // [2048, 1, 1739]

  // Workspace layout:
  float* ws = (float*)d_ws;
  float* xpe  = ws;                              // 2048*768
  float* xpd  = xpe + (size_t)TT * H3;           // 2048*768
  float* hs   = xpd + (size_t)TT * H3;           // 2048*256
  float* henc = hs + (size_t)TT * HN;            // 256
  _Float16* weh = (_Float16*)(henc + HN);        // [768][1760] f16
  _Float16* wdh = weh + (size_t)768 * IIP;       // [768][1760] f16
  _Float16* woh = wdh + (size_t)768 * IIP;       // [1739][256] f16
  uint* sync = (uint*)(woh + (size_t)II * HN);
  uint* slots_e = sync;                          // [2][2][64]
  uint* slots_d = sync + 256;                    // [2][2][64]
  uint* flags   = sync + 512;                    // enc @ +0/+64, dec @ +128/+192
  uint* el_e    = sync + 768;                    // cnt[8] + chosen
  uint* el_d    = sync + 784;

  // Zero flags + election state each launch (graph-capture-safe).
  hipMemsetAsync(flags, 0, (256 + 64) * sizeof(uint), stream);

  // One-time weight conversion to f16.
  prep_f16<<<dim3(1024), dim3(256), 0, stream>>>(Wih_e, Wih_d, Wout,
                                                 weh, wdh, woh);
  // g1: xpe projection (pre-scaled for exp2 gates).
  gemm16<<<dim3(12, 32), dim3(256), 0, stream>>>(x, II, weh, H3, IIP,
      bih_e, bhh_e, 2 * HN, L2E, 2.f * L2E, 2 * HN, xpe);
  // Encoder: elected same-XCD scan pair || xpd projection.
  fused_enc<<<dim3(NCAND + 384), dim3(512), 0, stream>>>(xpe, Whh_e, bhh_e,
      henc, slots_e, flags, el_e, x, wdh, bih_d, bhh_d, xpd);
  // Decoder: elected same-XCD scan pair -> hs.
  gru_pair<<<dim3(NCAND), dim3(512), 0, stream>>>(xpd, Whh_d, bhh_d, henc,
      hs, nullptr, slots_d, flags + 128, el_d);
  // g3: output projection.
  gemm16<<<dim3(28, 32), dim3(256), 0, stream>>>(hs, HN, woh, II, HN,
      bout, nullptr, 0, 1.f, 1.f, 0, out);
}

// Round 15
// 5107.677 us; speedup vs baseline: 2.4684x; 2.4684x over previous
//
#include <hip/hip_runtime.h>
#include <hip/hip_fp16.h>

// Problem constants
#define TT 2048
#define II 1739
#define IIP 1760              // II zero-padded to a multiple of 32 (f16 GEMM K)
#define HN 256
#define H3 768
#define L2E 1.44269504088896f

typedef _Float16 h2 __attribute__((ext_vector_type(2)));
typedef _Float16 h8 __attribute__((ext_vector_type(8)));
typedef float f4 __attribute__((ext_vector_type(4)));

__device__ __forceinline__ float fdot2(h2 a, h2 b, float c) {
#if defined(__has_builtin)
#if __has_builtin(__builtin_amdgcn_fdot2)
  return __builtin_amdgcn_fdot2(a, b, c, false);
#else
  return fmaf((float)a[0], (float)b[0], fmaf((float)a[1], (float)b[1], c));
#endif
#else
  return fmaf((float)a[0], (float)b[0], fmaf((float)a[1], (float)b[1], c));
#endif
}

__device__ __forceinline__ float fast_exp2(float x) {
#if defined(__has_builtin)
#if __has_builtin(__builtin_amdgcn_exp2f)
  return __builtin_amdgcn_exp2f(x);
#else
  return exp2f(x);
#endif
#else
  return exp2f(x);
#endif
}

__device__ __forceinline__ float fast_rcp(float x) {
#if defined(__has_builtin)
#if __has_builtin(__builtin_amdgcn_rcpf)
  return __builtin_amdgcn_rcpf(x);
#else
  return 1.f / x;
#endif
#else
  return 1.f / x;
#endif
}

template <int CTRL>
__device__ __forceinline__ float dpp_qperm(float v) {
  int r = __builtin_amdgcn_update_dpp(0, __builtin_bit_cast(int, v), CTRL, 0xF, 0xF, true);
  return __builtin_bit_cast(float, r);
}

__device__ __forceinline__ h8 h8zero() {
  h8 v;
#pragma unroll
  for (int j = 0; j < 8; ++j) v[j] = (_Float16)0.f;
  return v;
}

// ---------------------------------------------------------------------------
// One-time f32 -> f16 weight conversion (zero-padded K for the W_ih's).
// ---------------------------------------------------------------------------
#define WSEG (768 * IIP)
#define OSEG (II * HN)
__global__ __launch_bounds__(256) void prep_f16(
    const float* __restrict__ We, const float* __restrict__ Wd,
    const float* __restrict__ Wo,
    _Float16* __restrict__ weh, _Float16* __restrict__ wdh,
    _Float16* __restrict__ woh) {
  const int total = 2 * WSEG + OSEG;
  for (int i = blockIdx.x * 256 + threadIdx.x; i < total; i += gridDim.x * 256) {
    if (i < WSEG) {
      int r = i / IIP, k = i - r * IIP;
      weh[i] = (k < II) ? (_Float16)We[(size_t)r * II + k] : (_Float16)0.f;
    } else if (i < 2 * WSEG) {
      int j = i - WSEG;
      int r = j / IIP, k = j - r * IIP;
      wdh[j] = (k < II) ? (_Float16)Wd[(size_t)r * II + k] : (_Float16)0.f;
    } else {
      int j = i - 2 * WSEG;
      woh[j] = (_Float16)Wo[j];
    }
  }
}

// ---------------------------------------------------------------------------
// MFMA f16 GEMM tile body (r11, verified): C = ((A_f32 @ B16^T)+bias)*scale.
// 256 logical threads (512-thread callers pass tid&255: duplicate lanes redo
// identical work -- benign WAW with identical values, proven r10/r13).
// ---------------------------------------------------------------------------
__device__ __forceinline__ void gemm16_tile(
    int tid, int bx, int by,
    const float* __restrict__ A, int K,
    const _Float16* __restrict__ B16, int N, int Kp,
    const float* __restrict__ bias1, const float* __restrict__ bias2, int b2lim,
    float s_lo, float s_hi, int slim,
    float* __restrict__ C,
    _Float16 (*As)[40], _Float16 (*Bs)[40]) {
  const int w = tid >> 6, lane = tid & 63;
  const int col = lane & 15, kg = lane >> 4;
  const int m0 = by * 64, n0 = bx * 64;
  const int srow = tid >> 2, skq = tid & 3;
  f4 acc[4];
#pragma unroll
  for (int m = 0; m < 4; ++m) acc[m] = f4{0.f, 0.f, 0.f, 0.f};

  for (int k0 = 0; k0 < Kp; k0 += 32) {
    const int kk = k0 + skq * 8;
    h8 av = h8zero(), bv = h8zero();
    {
      const float* ap = A + (size_t)(m0 + srow) * K + kk;
      if (kk + 8 <= K) {
        float4 f0, f1;
        __builtin_memcpy(&f0, ap, 16);
        __builtin_memcpy(&f1, ap + 4, 16);
        av[0] = (_Float16)f0.x; av[1] = (_Float16)f0.y;
        av[2] = (_Float16)f0.z; av[3] = (_Float16)f0.w;
        av[4] = (_Float16)f1.x; av[5] = (_Float16)f1.y;
        av[6] = (_Float16)f1.z; av[7] = (_Float16)f1.w;
      } else if (kk < K) {
#pragma unroll
        for (int j = 0; j < 8; ++j)
          if (kk + j < K) av[j] = (_Float16)ap[j];
      }
    }
    {
      const int bn = n0 + srow;
      if (bn < N) bv = *(const h8*)(B16 + (size_t)bn * Kp + kk);
    }
    __syncthreads();
    *(h8*)&As[srow][skq * 8] = av;
    *(h8*)&Bs[srow][skq * 8] = bv;
    __syncthreads();
    h8 b = *(const h8*)&Bs[w * 16 + col][kg * 8];
#pragma unroll
    for (int m = 0; m < 4; ++m) {
      h8 a = *(const h8*)&As[m * 16 + col][kg * 8];
      acc[m] = __builtin_amdgcn_mfma_f32_16x16x32_f16(a, b, acc[m], 0, 0, 0);
    }
  }

  const int n = n0 + w * 16 + col;
  if (n < N) {
    float bb = bias1[n];
    if (bias2 && n < b2lim) bb += bias2[n];
    const float s = (n < slim) ? s_lo : s_hi;
#pragma unroll
    for (int m = 0; m < 4; ++m) {
      const int mr = m0 + m * 16 + kg * 4;
#pragma unroll
      for (int r = 0; r < 4; ++r)
        C[(size_t)(mr + r) * N + n] = (acc[m][r] + bb) * s;
    }
  }
}

__global__ __launch_bounds__(256) void gemm16(
    const float* __restrict__ A, int K,
    const _Float16* __restrict__ B16, int N, int Kp,
    const float* __restrict__ bias1, const float* __restrict__ bias2, int b2lim,
    float s_lo, float s_hi, int slim,
    float* __restrict__ C) {
  __shared__ _Float16 As[64][40];
  __shared__ _Float16 Bs[64][40];
  gemm16_tile(threadIdx.x, blockIdx.x, blockIdx.y, A, K, B16, N, Kp,
              bias1, bias2, b2lim, s_lo, s_hi, slim, C, As, Bs);
}

// ---------------------------------------------------------------------------
// Sequential GRU scan -- EXACT round-4/round-11 body (best verified:
// 2140-2200 us/scan, absmax exactly 0.0078125). Single CU, 512 threads;
// quad q owns units {2q, 2q+1} for all three gates; one __syncthreads per
// step; double-buffered f16 h at chunk-stride 40; exp2-form gates with
// pre-scaled args. hbufd passed in (2*160 dwords) so fused callers can
// declare their own LDS.
// ---------------------------------------------------------------------------
__device__ void gru_scan(
    const float* __restrict__ xp,      // [T, 768], pre-scaled by L2E/2L2E
    const float* __restrict__ Whh,     // [768, 256]
    const float* __restrict__ bhh,     // [768]
    const float* __restrict__ h0,      // [256] or nullptr (zeros)
    float* __restrict__ hs_out,        // [T, 256] or nullptr
    float* __restrict__ hT_out,        // [256] or nullptr
    uint* hbufd /* LDS, 2*160 dwords */) {
  const int tid = threadIdx.x;
  const int lane = tid & 63;
  const int wv = tid >> 6;              // 0..7
  const int kc = lane & 3;              // k-chunk [64*kc, 64*kc+64)
  const int q = wv * 16 + (lane >> 2);  // 0..127; units 2q, 2q+1
  const int u0 = 2 * q;

  // wreg[uu*3+gg]: unit u0+uu, gate gg (0=r,1=z,2=n), pre-scaled.
  h2 wreg[6][32];
#pragma unroll
  for (int uu = 0; uu < 2; ++uu) {
#pragma unroll
    for (int gg = 0; gg < 3; ++gg) {
      const float sc = (gg == 2) ? (2.f * L2E) : L2E;
      const float* wr = Whh + (size_t)(u0 + uu + gg * HN) * HN + kc * 64;
#pragma unroll
      for (int p = 0; p < 32; ++p) {
        float2 f = *(const float2*)(wr + 2 * p);
        wreg[uu * 3 + gg][p] = h2{(_Float16)(f.x * sc), (_Float16)(f.y * sc)};
      }
    }
  }

  float hj0 = h0 ? h0[u0] : 0.f;
  float hj1 = h0 ? h0[u0 + 1] : 0.f;
  const float bhn0 = bhh[2 * HN + u0] * (2.f * L2E);
  const float bhn1 = bhh[2 * HN + u0 + 1] * (2.f * L2E);

  if (tid < 128) {
    float a = h0 ? h0[2 * tid] : 0.f;
    float b = h0 ? h0[2 * tid + 1] : 0.f;
    h2 pv = h2{(_Float16)a, (_Float16)b};
    hbufd[(tid >> 5) * 40 + (tid & 31)] = __builtin_bit_cast(uint, pv);
  }
  __syncthreads();

  const int wadr = (q >> 5) * 40 + (q & 31);

  for (int t = 0; t < TT; ++t) {
    const int cur = (t & 1) * 160, nxt = ((t + 1) & 1) * 160;
    // This step's x-projection (issued early; lands during the matvec).
    float2 xr, xz, xn;
    {
      const float* xpt = xp + (size_t)t * H3 + u0;
      xr = *(const float2*)(xpt);
      xz = *(const float2*)(xpt + HN);
      xn = *(const float2*)(xpt + 2 * HN);
    }

    // Matvec: 6 rows x 64 k per thread (f16 dot2, fp32 accumulate).
    const uint* hb = &hbufd[cur + kc * 40];
    float a[6] = {0.f, 0.f, 0.f, 0.f, 0.f, 0.f};
#pragma unroll
    for (int qq = 0; qq < 8; ++qq) {
      uint4 v = *(const uint4*)&hb[qq * 4];
      uint hwv[4] = {v.x, v.y, v.z, v.w};
#pragma unroll
      for (int i = 0; i < 6; ++i)
#pragma unroll
        for (int p = 0; p < 4; ++p)
          a[i] = fdot2(wreg[i][qq * 4 + p], __builtin_bit_cast(h2, hwv[p]), a[i]);
    }

    // Quad butterfly: all 4 lanes end with the full k-sum (bit-identical).
#pragma unroll
    for (int i = 0; i < 6; ++i) {
      float v = a[i];
      v += dpp_qperm<0xB1>(v);  // xor 1
      v += dpp_qperm<0x4E>(v);  // xor 2
      a[i] = v;
    }

    // Gates, fully local (args pre-scaled by log2e / 2log2e).
    float r0 = fast_rcp(1.f + fast_exp2(-(xr.x + a[0])));
    float z0 = fast_rcp(1.f + fast_exp2(-(xz.x + a[1])));
    float n0 = fmaf(2.f, fast_rcp(1.f + fast_exp2(-fmaf(r0, a[2] + bhn0, xn.x))), -1.f);
    hj0 = fmaf(z0, hj0 - n0, n0);
    float r1 = fast_rcp(1.f + fast_exp2(-(xr.y + a[3])));
    float z1 = fast_rcp(1.f + fast_exp2(-(xz.y + a[4])));
    float n1 = fmaf(2.f, fast_rcp(1.f + fast_exp2(-fmaf(r1, a[5] + bhn1, xn.y))), -1.f);
    hj1 = fmaf(z1, hj1 - n1, n1);

    h2 pv = h2{(_Float16)hj0, (_Float16)hj1};
    if (kc == 0) {
      hbufd[nxt + wadr] = __builtin_bit_cast(uint, pv);
      if (hs_out) *(float2*)&hs_out[(size_t)t * HN + u0] = make_float2(hj0, hj1);
    }
    __syncthreads();
  }
  if (hT_out && kc == 0) *(float2*)&hT_out[u0] = make_float2(hj0, hj1);
}

// Standalone decoder scan (1 block, 512 threads).
__global__ __launch_bounds__(512) void gru_seq(
    const float* __restrict__ xp, const float* __restrict__ Whh,
    const float* __restrict__ bhh, const float* __restrict__ h0,
    float* __restrict__ hs_out, float* __restrict__ hT_out) {
  __shared__ __align__(16) uint hbufd[2 * 160];
  gru_scan(xp, Whh, bhh, h0, hs_out, hT_out, hbufd);
}

// ---------------------------------------------------------------------------
// F1 fusion (r10-proven pattern): encoder scan (block 0) + xpd projection
// (blocks 1..384, free-running, no inter-block communication -> safe under
// any dispatch order; measured non-interfering with the scan in r10/r13).
// ---------------------------------------------------------------------------
__global__ __launch_bounds__(512) void fused_enc(
    const float* __restrict__ xpe, const float* __restrict__ Whh_e,
    const float* __restrict__ bhh_e, float* __restrict__ henc,
    const float* __restrict__ x, const _Float16* __restrict__ wdh,
    const float* __restrict__ bih_d, const float* __restrict__ bhh_d,
    float* __restrict__ xpd) {
  __shared__ __align__(16) uint hbufd[2 * 160];
  __shared__ _Float16 As[64][40];
  __shared__ _Float16 Bs[64][40];
  if (blockIdx.x == 0) {
    gru_scan(xpe, Whh_e, bhh_e, nullptr, nullptr, henc, hbufd);
  } else {
    const int bb = blockIdx.x - 1;  // 0..383
    gemm16_tile(threadIdx.x & 255, bb % 12, bb / 12, x, II, wdh, H3, IIP,
                bih_d, bhh_d, 2 * HN, L2E, 2.f * L2E, 2 * HN, xpd, As, Bs);
  }
}

extern "C" void kernel_launch(void* const* d_in, const int* in_sizes, int n_in,
                              void* d_out, int out_size, void* d_ws, size_t ws_size,
                              hipStream_t stream) {
  const float* x     = (const float*)d_in[0];   // [1, 2048, 1739]
  const float* Wih_e = (const float*)d_in[2];   // [768, 1739]
  const float* Whh_e = (const float*)d_in[3];   // [768, 256]
  const float* bih_e = (const float*)d_in[4];   // [768]
  const float* bhh_e = (const float*)d_in[5];   // [768]
  const float* Wih_d = (const float*)d_in[6];
  const float* Whh_d = (const float*)d_in[7];
  const float* bih_d = (const float*)d_in[8];
  const float* bhh_d = (const float*)d_in[9];
  const float* Wout  = (const float*)d_in[10];  // [1739, 256]
  const float* bout  = (const float*)d_in[11];  // [1739]
  float* out = (float*)d_out;                   // [2048, 1, 1739]

  // Workspace layout (floats; all segment starts 16B-aligned):
  float* ws = (float*)d_ws;
  float* xpe  = ws;                              // 2048*768
  float* xpd  = xpe + (size_t)TT * H3;           // 2048*768
  float* hs   = xpd + (size_t)TT * H3;           // 2048*256
  float* henc = hs + (size_t)TT * HN;            // 256
  _Float16* weh = (_Float16*)(henc + HN);        // [768][1760] f16
  _Float16* wdh = weh + (size_t)768 * IIP;       // [768][1760] f16
  _Float16* woh = wdh + (size_t)768 * IIP;       // [1739][256] f16

  // One-time weight conversion to f16 (zero-padded K for the W_ih's).
  prep_f16<<<dim3(1024), dim3(256), 0, stream>>>(Wih_e, Wih_d, Wout,
                                                 weh, wdh, woh);
  // g1: xpe projection via MFMA f16, pre-scaled for exp2-based gates:
  //   rows [0,512) (r,z): (x@W^T + bih + bhh) * log2e
  //   rows [512,768) (n): (x@W^T + bih) * 2log2e   (bhh n-part in-gate)
  gemm16<<<dim3(12, 32), dim3(256), 0, stream>>>(x, II, weh, H3, IIP,
      bih_e, bhh_e, 2 * HN, L2E, 2.f * L2E, 2 * HN, xpe);
  // Encoder scan (block 0) || xpd projection (blocks 1..384).
  fused_enc<<<dim3(385), dim3(512), 0, stream>>>(xpe, Whh_e, bhh_e, henc,
                                                 x, wdh, bih_d, bhh_d, xpd);
  // Decoder scan -> hs.
  gru_seq<<<1, 512, 0, stream>>>(xpd, Whh_d, bhh_d, henc, hs, nullptr);
  // g3: output projection via MFMA f16 (unscaled).
  gemm16<<<dim3(28, 32), dim3(256), 0, stream>>>(hs, HN, woh, II, HN,
      bout, nullptr, 0, 1.f, 1.f, 0, out);
}